// Round 2
// baseline (2044.455 us; speedup 1.0000x reference)
//
#include <hip/hip_runtime.h>
#include <hip/hip_bf16.h>

// Problem constants (G=8, H=4096, I=1536, M=16384, m_splits=2048)
#define G_  8
#define H_  4096
#define I_  1536
#define MS_ 2048

typedef float  f32x4  __attribute__((ext_vector_type(4)));
typedef __bf16 bf16x8 __attribute__((ext_vector_type(8)));
typedef unsigned int   u32;
typedef unsigned short u16;

#define LDS8(p) (*(const bf16x8*)(p))

// 8 fp32 -> 8 bf16 (RNE) packed in a uint4, via v_cvt_pk_bf16_f32.
__device__ __forceinline__ uint4 cvt8(float4 a, float4 b) {
    uint4 r;
    asm("v_cvt_pk_bf16_f32 %0, %1, %2" : "=v"(r.x) : "v"(a.x), "v"(a.y));
    asm("v_cvt_pk_bf16_f32 %0, %1, %2" : "=v"(r.y) : "v"(a.z), "v"(a.w));
    asm("v_cvt_pk_bf16_f32 %0, %1, %2" : "=v"(r.z) : "v"(b.x), "v"(b.y));
    asm("v_cvt_pk_bf16_f32 %0, %1, %2" : "=v"(r.w) : "v"(b.z), "v"(b.w));
    return r;
}

// ---------------------------------------------------------------------------
// Fused fp32 grouped GEMM + SwiGLU, single kernel (no cvt passes, no ws).
// Block: 512 threads = 8 waves (2 row x 4 col). Tile: 256 rows x (128 gate +
// 128 up) cols, BK=64, double-buffered 128 KiB LDS (bf16 after in-reg cvt).
// LDS layout (u16 elems): A0 [0,16384) A1 [16384,32768) B0 [32768,49152)
// B1 [49152,65536); rows 64 elems (128 B); eight 16 B chunks per row
// XOR-swizzled by (row&7) (T2) on BOTH ds_write and ds_read addresses.
// Per K-tile, 4 phases as in the verified round-1 schedule; staging is now
// reg-path: B fp32 loads issued at kstep start, A loads in ph2; converts +
// swizzled ds_write_b128 land region-by-region (gate@ph2, up@ph3, A@ph4) --
// exactly where the old async16s went, so the overwrite hazard analysis is
// unchanged. Compiler inserts counted vmcnt before each cvt use.
// ---------------------------------------------------------------------------
template <bool STAGE>
__device__ __forceinline__ void kstep(
    f32x4 (&accg)[8][2], f32x4 (&accu)[8][2],
    const u16* __restrict__ Ar, const u16* __restrict__ Br,
    u16* Aw, u16* Bw,
    const float*& aP, const float*& gP, const float*& uP,
    int la0, int lw)
{
    __builtin_amdgcn_s_barrier();
    __builtin_amdgcn_sched_barrier(0);

    bf16x8 af[4][2], bg[2][2], bu[2][2];
    float4 sg[4], su[4], sa[8];

    if (STAGE) {   // issue B fp32 loads (gate 4, up 4)
        sg[0] = *(const float4*)(gP);
        sg[1] = *(const float4*)(gP + 4);
        sg[2] = *(const float4*)(gP + (size_t)64 * H_);
        sg[3] = *(const float4*)(gP + (size_t)64 * H_ + 4);
        su[0] = *(const float4*)(uP);
        su[1] = *(const float4*)(uP + 4);
        su[2] = *(const float4*)(uP + (size_t)64 * H_);
        su[3] = *(const float4*)(uP + (size_t)64 * H_ + 4);
    }

    // ---- phase 1: read A(mh0)+B_gate (12 ds_read_b128); MFMA gate mh0
#pragma unroll
    for (int tt = 0; tt < 4; ++tt) {
        af[tt][0] = LDS8(Ar + tt * 1024 + la0);
        af[tt][1] = LDS8(Ar + tt * 1024 + (la0 ^ 32));
    }
#pragma unroll
    for (int nt = 0; nt < 2; ++nt) {
        bg[nt][0] = LDS8(Br + nt * 1024 + la0);
        bg[nt][1] = LDS8(Br + nt * 1024 + (la0 ^ 32));
    }
    asm volatile("s_waitcnt lgkmcnt(8)" ::: "memory");
    __builtin_amdgcn_s_barrier();
    asm volatile("s_waitcnt lgkmcnt(0)" ::: "memory");
    __builtin_amdgcn_sched_barrier(0);
    __builtin_amdgcn_s_setprio(1);
#pragma unroll
    for (int tt = 0; tt < 4; ++tt)
#pragma unroll
        for (int nt = 0; nt < 2; ++nt)
#pragma unroll
            for (int ks = 0; ks < 2; ++ks)
                accg[tt][nt] = __builtin_amdgcn_mfma_f32_16x16x32_bf16(
                    af[tt][ks], bg[nt][ks], accg[tt][nt], 0, 0, 0);
    __builtin_amdgcn_s_setprio(0);
    __builtin_amdgcn_s_barrier();

    // ---- phase 2: read B_up (4); issue A loads; cvt+write gate (drained @ph1)
#pragma unroll
    for (int nt = 0; nt < 2; ++nt) {
        bu[nt][0] = LDS8(Br + 8192 + nt * 1024 + la0);
        bu[nt][1] = LDS8(Br + 8192 + nt * 1024 + (la0 ^ 32));
    }
    if (STAGE) {
#pragma unroll
        for (int s = 0; s < 4; ++s) {
            sa[2 * s]     = *(const float4*)(aP + (size_t)(s * 64) * H_);
            sa[2 * s + 1] = *(const float4*)(aP + (size_t)(s * 64) * H_ + 4);
        }
        *(uint4*)(Bw + lw)        = cvt8(sg[0], sg[1]);   // gate slab 0
        *(uint4*)(Bw + 4096 + lw) = cvt8(sg[2], sg[3]);   // gate slab 1
    }
    __builtin_amdgcn_s_barrier();
    asm volatile("s_waitcnt lgkmcnt(0)" ::: "memory");
    __builtin_amdgcn_sched_barrier(0);
    __builtin_amdgcn_s_setprio(1);
#pragma unroll
    for (int tt = 0; tt < 4; ++tt)
#pragma unroll
        for (int nt = 0; nt < 2; ++nt)
#pragma unroll
            for (int ks = 0; ks < 2; ++ks)
                accu[tt][nt] = __builtin_amdgcn_mfma_f32_16x16x32_bf16(
                    af[tt][ks], bu[nt][ks], accu[tt][nt], 0, 0, 0);
    __builtin_amdgcn_s_setprio(0);
    __builtin_amdgcn_s_barrier();

    // ---- phase 3: read A(mh1) (8); cvt+write up (drained @ph2); MFMA gate mh1
#pragma unroll
    for (int tt = 0; tt < 4; ++tt) {
        af[tt][0] = LDS8(Ar + 4096 + tt * 1024 + la0);
        af[tt][1] = LDS8(Ar + 4096 + tt * 1024 + (la0 ^ 32));
    }
    if (STAGE) {
        *(uint4*)(Bw + 8192 + lw)  = cvt8(su[0], su[1]);  // up slab 0
        *(uint4*)(Bw + 12288 + lw) = cvt8(su[2], su[3]);  // up slab 1
    }
    __builtin_amdgcn_s_barrier();
    asm volatile("s_waitcnt lgkmcnt(0)" ::: "memory");
    __builtin_amdgcn_sched_barrier(0);
    __builtin_amdgcn_s_setprio(1);
#pragma unroll
    for (int tt = 0; tt < 4; ++tt)
#pragma unroll
        for (int nt = 0; nt < 2; ++nt)
#pragma unroll
            for (int ks = 0; ks < 2; ++ks)
                accg[4 + tt][nt] = __builtin_amdgcn_mfma_f32_16x16x32_bf16(
                    af[tt][ks], bg[nt][ks], accg[4 + tt][nt], 0, 0, 0);
    __builtin_amdgcn_s_setprio(0);
    __builtin_amdgcn_s_barrier();

    // ---- phase 4: cvt+write A (drained @ph3); MFMA up mh1 (regs only)
    if (STAGE) {
#pragma unroll
        for (int s = 0; s < 4; ++s)
            *(uint4*)(Aw + s * 4096 + lw) = cvt8(sa[2 * s], sa[2 * s + 1]);
    }
    __builtin_amdgcn_s_barrier();
    __builtin_amdgcn_s_setprio(1);
#pragma unroll
    for (int tt = 0; tt < 4; ++tt)
#pragma unroll
        for (int nt = 0; nt < 2; ++nt)
#pragma unroll
            for (int ks = 0; ks < 2; ++ks)
                accu[4 + tt][nt] = __builtin_amdgcn_mfma_f32_16x16x32_bf16(
                    af[tt][ks], bu[nt][ks], accu[4 + tt][nt], 0, 0, 0);
    __builtin_amdgcn_s_setprio(0);

    if (STAGE) { aP += 64; gP += 64; uP += 64; }
}

// Prologue: full tile stage (16 fp32x4 loads -> cvt -> swizzled ds_write).
__device__ __forceinline__ void stage_tile(
    const float* aP, const float* gP, const float* uP,
    u16* Aw, u16* Bw, int lw)
{
    float4 v[16];
#pragma unroll
    for (int s = 0; s < 4; ++s) {
        v[2 * s]     = *(const float4*)(aP + (size_t)(s * 64) * H_);
        v[2 * s + 1] = *(const float4*)(aP + (size_t)(s * 64) * H_ + 4);
    }
    v[8]  = *(const float4*)(gP);
    v[9]  = *(const float4*)(gP + 4);
    v[10] = *(const float4*)(gP + (size_t)64 * H_);
    v[11] = *(const float4*)(gP + (size_t)64 * H_ + 4);
    v[12] = *(const float4*)(uP);
    v[13] = *(const float4*)(uP + 4);
    v[14] = *(const float4*)(uP + (size_t)64 * H_);
    v[15] = *(const float4*)(uP + (size_t)64 * H_ + 4);
#pragma unroll
    for (int s = 0; s < 4; ++s)
        *(uint4*)(Aw + s * 4096 + lw) = cvt8(v[2 * s], v[2 * s + 1]);
    *(uint4*)(Bw + lw)         = cvt8(v[8],  v[9]);
    *(uint4*)(Bw + 4096 + lw)  = cvt8(v[10], v[11]);
    *(uint4*)(Bw + 8192 + lw)  = cvt8(v[12], v[13]);
    *(uint4*)(Bw + 12288 + lw) = cvt8(v[14], v[15]);
}

__global__ __launch_bounds__(512, 2) void gemm_swiglu_f32(
    const float* __restrict__ x, const float* __restrict__ w,
    float* __restrict__ out)
{
    __shared__ u16 lds[65536];   // 128 KiB

    // T1: group = blockid&7 pins group<->XCD. Within a group, 4rt x 6ct
    // supertiles, ct-fastest; W-sharing supertiles (same ct band) adjacent.
    const int d  = blockIdx.x;
    const int g  = d & 7;
    const int q  = d >> 3;            // 0..95
    const int t4 = q / 24;            // 0..3
    const int u  = q - t4 * 24;       // 0..23
    const int rt = (t4 & 1) * 4 + u / 6;       // 0..7
    const int ct = (t4 >> 1) * 6 + u % 6;      // 0..11
    const int n0 = ct * 128;

    const int tid  = threadIdx.x;
    const int lane = tid & 63;
    const int wv   = tid >> 6;
    const int wr   = wv >> 2;         // 0..1 wave row
    const int wc   = wv & 3;          // 0..3 wave col
    const int fr   = lane & 15;
    const int kq4  = lane >> 4;
    // ds_read base: row fr, chunk (kq4 ^ (row&7)) -- T2 swizzle
    const int la0  = fr * 64 + ((kq4 ^ (fr & 7)) * 8);
    // staging: thread covers LDS local row (tid>>3) per 64-row slab, logical
    // chunk tid&7 -> phys chunk XOR'd by row&7 (same involution as read side)
    const int lrow = tid >> 3;                 // 0..63
    const int lch  = tid & 7;
    const int lw   = lrow * 64 + (((lch ^ (lrow & 7))) * 8);

    const float* xb = x + ((size_t)g * MS_ + (size_t)rt * 256) * H_;
    const float* wb = w + (size_t)g * (2 * I_) * H_;

    // wave-local LDS read bases
    const u16* A0r = lds + wr * 8192;
    const u16* A1r = A0r + 16384;
    const u16* B0r = lds + 32768 + wc * 2048;
    const u16* B1r = B0r + 16384;
    // write bases (thread offset lw applied inside)
    u16* A0w = lds;
    u16* A1w = lds + 16384;
    u16* B0w = lds + 32768;
    u16* B1w = lds + 49152;

    f32x4 accg[8][2], accu[8][2];
#pragma unroll
    for (int i = 0; i < 8; ++i)
#pragma unroll
        for (int j = 0; j < 2; ++j) {
            accg[i][j] = f32x4{0.f, 0.f, 0.f, 0.f};
            accu[i][j] = f32x4{0.f, 0.f, 0.f, 0.f};
        }

    const float* aP = xb + (size_t)lrow * H_ + lch * 8;
    const float* gP = wb + (size_t)(n0 + lrow) * H_ + lch * 8;
    const float* uP = wb + ((size_t)I_ + n0 + lrow) * H_ + lch * 8;

    // prologue: stage K-tile 0 -> buf0, K-tile 1 -> buf1
    stage_tile(aP,      gP,      uP,      A0w, B0w, lw);
    stage_tile(aP + 64, gP + 64, uP + 64, A1w, B1w, lw);
    aP += 128; gP += 128; uP += 128;    // -> k-chunk for tile 2
    asm volatile("s_waitcnt lgkmcnt(0)" ::: "memory");
    __builtin_amdgcn_s_barrier();

    // main loop: K = 4096 = 64 K-tiles; ksteps 0..61 stage tile t+2
#pragma unroll 1
    for (int it = 0; it < 31; ++it) {
        kstep<true>(accg, accu, A0r, B0r, A0w, B0w, aP, gP, uP, la0, lw);
        kstep<true>(accg, accu, A1r, B1r, A1w, B1w, aP, gP, uP, la0, lw);
    }
    kstep<false>(accg, accu, A0r, B0r, A0w, B0w, aP, gP, uP, la0, lw);  // kt=62
    kstep<false>(accg, accu, A1r, B1r, A1w, B1w, aP, gP, uP, la0, lw);  // kt=63

    // epilogue: C/D layout col = lane&15, row = (lane>>4)*4 + i  [m89-verified]
    const size_t orow0 = (size_t)g * MS_ + rt * 256 + wr * 128 + (lane >> 4) * 4;
    const int    ocol  = n0 + wc * 32 + fr;
#pragma unroll
    for (int mt = 0; mt < 8; ++mt)
#pragma unroll
        for (int nt = 0; nt < 2; ++nt)
#pragma unroll
            for (int i = 0; i < 4; ++i) {
                float gv = accg[mt][nt][i];
                float uv = accu[mt][nt][i];
                float s  = gv / (1.0f + __expf(-gv));   // silu(gate)
                out[(orow0 + mt * 16 + i) * I_ + (ocol + nt * 16)] = s * uv;
            }
}

extern "C" void kernel_launch(void* const* d_in, const int* in_sizes, int n_in,
                              void* d_out, int out_size, void* d_ws, size_t ws_size,
                              hipStream_t stream) {
    const float* x = (const float*)d_in[0];
    const float* w = (const float*)d_in[1];
    float* out = (float*)d_out;
    (void)d_ws; (void)ws_size;

    gemm_swiglu_f32<<<dim3(768), dim3(512), 0, stream>>>(x, w, out);
}